// Round 5
// baseline (303.153 us; speedup 1.0000x reference)
//
#include <hip/hip_runtime.h>
#include <stdint.h>

// B=131072 rows, K=IN=256, N=OUT=256.
// temp = act @ weight.T (exact int32, |t| < 2^24); r = max|temp|;
// bw = ceil(log2(max(r,1))) (0 if r<=1); shift = bw-7;
// shift>0 ? round_shift(temp,shift) clipped to [-127,127] : int8-wrap(temp)
// exp_out = exp_in + weight_exp + max(shift,0)  (int16 semantics)
// Harness reads d_out as INT32: [B*N values, 1 exp scalar].

#define M_ROWS 131072
#define NK 256
#define BM 64
#define BK 64
#define BKP 72      // padded LDS row stride (bf16 elems) = 144 B

typedef __attribute__((ext_vector_type(8))) short bf16x8;
typedef __attribute__((ext_vector_type(4))) float f32x4;
typedef __attribute__((ext_vector_type(4))) float fv4;
typedef __attribute__((ext_vector_type(4))) int iv4;
typedef __attribute__((ext_vector_type(4))) unsigned int u32x4;
typedef __attribute__((ext_vector_type(4))) unsigned short us4;

__device__ __forceinline__ uint32_t pack_bf16(float a, float b) {
  // exact for integer-valued floats |v| <= 255
  return (__float_as_uint(a) >> 16) | (__float_as_uint(b) & 0xFFFF0000u);
}

// Prepass: weight fp32 -> bf16 (65536 elems, 64 blocks x 256 thr x 4 elems)
__global__ void wconv(const float* __restrict__ w, unsigned short* __restrict__ wb) {
  const int i = blockIdx.x * 256 + threadIdx.x;
  const fv4 f = ((const fv4*)w)[i];
  us4 o;
  o.x = (unsigned short)(__float_as_uint(f.x) >> 16);
  o.y = (unsigned short)(__float_as_uint(f.y) >> 16);
  o.z = (unsigned short)(__float_as_uint(f.z) >> 16);
  o.w = (unsigned short)(__float_as_uint(f.w) >> 16);
  ((us4*)wb)[i] = o;
}

// Pass 1: GEMM -> int32 temp (nt stores) + global abs-max.
// 256 threads (4 waves); block tile 64 x 256 (full N); wave w: cols w*64..+63.
__global__ __launch_bounds__(256, 3) void gemm_pass1(
    const float* __restrict__ act,           // [M,256] int-valued fp32 (nt)
    const unsigned short* __restrict__ wgtb, // [256,256] bf16 (L2-resident)
    int* __restrict__ temp,                  // [M,256] int32 out (nt)
    int* __restrict__ gmax)                  // [1] global abs-max (pre-zeroed)
{
  __shared__ __align__(16) short As[BM * BKP];   //  9216 B
  __shared__ __align__(16) short Bs[NK * BKP];   // 36864 B
  __shared__ int smax;

  const int tid = threadIdx.x;
  if (tid == 0) smax = 0;

  const int bm   = blockIdx.x * BM;
  const int lane = tid & 63;
  const int wave = tid >> 6;
  const int lm   = lane & 15;
  const int lk   = lane >> 4;
  const int wn   = wave * 64;

  // A: 2 chunks/thread (8 fp32 -> 8 bf16).  arow 0..31, +32 for j=1.
  // B: 8 chunks/thread (8 bf16 = one u32x4). brow 0..31, +32*j, j=0..7.
  const int arow = tid >> 3, aks = (tid & 7) * 8;
  const int brow = tid >> 3, bks = (tid & 7) * 8;

  uint32_t apk[2][4];
  u32x4 breg[8];

  // ---- preload k-tile 0 into registers ----
#pragma unroll
  for (int j = 0; j < 2; ++j) {
    const float* p = act + (size_t)(bm + arow + j * 32) * NK + aks;
    const fv4 f0 = __builtin_nontemporal_load((const fv4*)p);
    const fv4 f1 = __builtin_nontemporal_load((const fv4*)p + 1);
    apk[j][0] = pack_bf16(f0.x, f0.y); apk[j][1] = pack_bf16(f0.z, f0.w);
    apk[j][2] = pack_bf16(f1.x, f1.y); apk[j][3] = pack_bf16(f1.z, f1.w);
  }
#pragma unroll
  for (int j = 0; j < 8; ++j)
    breg[j] = *(const u32x4*)(wgtb + (size_t)(brow + j * 32) * NK + bks);

  f32x4 acc[4][4] = {};

  for (int kt = 0; kt < NK; kt += BK) {
    __syncthreads();   // prior tile's LDS readers done
#pragma unroll
    for (int j = 0; j < 2; ++j)
      *(u32x4*)&As[(arow + j * 32) * BKP + aks] = *(const u32x4*)apk[j];
#pragma unroll
    for (int j = 0; j < 8; ++j)
      *(u32x4*)&Bs[(brow + j * 32) * BKP + bks] = breg[j];
    __syncthreads();

    // issue next k-tile's global loads (in flight under the MFMAs)
    if (kt + BK < NK) {
      const int ktn = kt + BK;
#pragma unroll
      for (int j = 0; j < 2; ++j) {
        const float* p = act + (size_t)(bm + arow + j * 32) * NK + ktn + aks;
        const fv4 f0 = __builtin_nontemporal_load((const fv4*)p);
        const fv4 f1 = __builtin_nontemporal_load((const fv4*)p + 1);
        apk[j][0] = pack_bf16(f0.x, f0.y); apk[j][1] = pack_bf16(f0.z, f0.w);
        apk[j][2] = pack_bf16(f1.x, f1.y); apk[j][3] = pack_bf16(f1.z, f1.w);
      }
#pragma unroll
      for (int j = 0; j < 8; ++j)
        breg[j] = *(const u32x4*)(wgtb + (size_t)(brow + j * 32) * NK + ktn + bks);
    }

#pragma unroll
    for (int kk = 0; kk < BK; kk += 32) {
      bf16x8 af[4], bfr[4];
#pragma unroll
      for (int mi = 0; mi < 4; ++mi)
        af[mi] = *(const bf16x8*)&As[(mi * 16 + lm) * BKP + kk + lk * 8];
#pragma unroll
      for (int ni = 0; ni < 4; ++ni)
        bfr[ni] = *(const bf16x8*)&Bs[(wn + ni * 16 + lm) * BKP + kk + lk * 8];
#pragma unroll
      for (int mi = 0; mi < 4; ++mi)
#pragma unroll
        for (int ni = 0; ni < 4; ++ni)
          acc[mi][ni] = __builtin_amdgcn_mfma_f32_16x16x32_bf16(
              af[mi], bfr[ni], acc[mi][ni], 0, 0, 0);
    }
  }

  // Epilogue: C/D layout col = lane&15, row = (lane>>4)*4 + reg  [m89]
  int imax = 0;
#pragma unroll
  for (int mi = 0; mi < 4; ++mi)
#pragma unroll
    for (int ni = 0; ni < 4; ++ni)
#pragma unroll
      for (int r = 0; r < 4; ++r) {
        const float v = acc[mi][ni][r];
        const int iv = (int)v;
        const int m = bm + mi * 16 + lk * 4 + r;
        const int n = wn + ni * 16 + lm;
        __builtin_nontemporal_store(iv, &temp[(size_t)m * NK + n]);
        const int a = iv < 0 ? -iv : iv;
        imax = a > imax ? a : imax;
      }
  // wave shuffle-reduce, then one LDS atomic per wave
#pragma unroll
  for (int off = 32; off; off >>= 1) {
    const int o = __shfl_xor(imax, off, 64);
    imax = o > imax ? o : imax;
  }
  if (lane == 0) atomicMax(&smax, imax);
  __syncthreads();
  if (tid == 0) atomicMax(gmax, smax);
}

// Pass 2: in-place quantize int32 temp -> int32 int8-value; write exp scalar.
__global__ void quant_pass2(int* __restrict__ temp,
                            const int* __restrict__ gmax,
                            const int* __restrict__ exp_in,
                            const int* __restrict__ wexp)
{
  const int r = *gmax;
  const int bw = (r <= 1) ? 0 : (32 - __clz(r - 1));   // ceil(log2(r))
  const int shift = bw - 7;
  const bool pos = shift > 0;
  const int s = shift < 1 ? 1 : shift;

  const int total4 = (M_ROWS * NK) / 4;   // 8388608
  iv4* p = (iv4*)temp;
  const int idx = blockIdx.x * blockDim.x + threadIdx.x;
  const int stride = gridDim.x * blockDim.x;

  for (int i = idx; i < total4; i += stride) {
    const iv4 t = __builtin_nontemporal_load(&p[i]);
    iv4 o;
#pragma unroll
    for (int j = 0; j < 4; ++j) {
      const int ti = t[j];
      int q;
      if (pos) {
        const int rt = ti >> s;                       // floor(t / 2^s)
        const int dec = (ti - (rt << s)) >> (s - 1);  // {0,1}
        q = rt + dec;
        q = q > 127 ? 127 : (q < -127 ? -127 : q);
      } else {
        q = (int)(signed char)(ti & 0xFF);
      }
      o[j] = q;
    }
    __builtin_nontemporal_store(o, &p[i]);
  }

  if (idx == 0) {
    const int e = exp_in[0] + wexp[0] + (pos ? shift : 0);
    temp[(size_t)M_ROWS * NK] = (int)(short)e;
  }
}

extern "C" void kernel_launch(void* const* d_in, const int* in_sizes, int n_in,
                              void* d_out, int out_size, void* d_ws, size_t ws_size,
                              hipStream_t stream) {
  const float* act   = (const float*)d_in[0];
  const int* exp_in  = (const int*)d_in[1];
  const float* wgt   = (const float*)d_in[2];
  const int* wexp    = (const int*)d_in[3];
  int* gmax          = (int*)d_ws;
  unsigned short* wb = (unsigned short*)((char*)d_ws + 128);  // 128 KB bf16 weight

  (void)hipMemsetAsync(d_ws, 0, sizeof(int), stream);
  wconv<<<dim3(64), dim3(256), 0, stream>>>(wgt, wb);
  gemm_pass1<<<dim3(M_ROWS / BM), dim3(256), 0, stream>>>(act, wb, (int*)d_out, gmax);
  quant_pass2<<<dim3(4096), dim3(256), 0, stream>>>((int*)d_out, gmax, exp_in, wexp);
}

// Round 6
// 281.432 us; speedup vs baseline: 1.0772x; 1.0772x over previous
//
#include <hip/hip_runtime.h>
#include <stdint.h>

// B=131072 rows, K=IN=256, N=OUT=256.
// temp = act @ weight.T (exact int32, |t| < 2^24); r = max|temp|;
// bw = ceil(log2(max(r,1))) (0 if r<=1); shift = bw-7;
// shift>0 ? round_shift(temp,shift) clipped to [-127,127] : int8-wrap(temp)
// exp_out = exp_in + weight_exp + max(shift,0)  (int16 semantics)
// Harness reads d_out as INT32: [B*N values, 1 exp scalar].
//
// Strategy: NO temp buffer. k1 = GEMM -> abs-max only (no stores).
// k2 = recompute GEMM (act re-read hits Infinity Cache), quantize in regs,
// nt-store final int32 once. HBM floor ~268 MB vs ~670 MB for materialize.

#define M_ROWS 131072
#define NK 256
#define BM 64
#define BK 64
#define BKP 72      // padded LDS row stride (bf16 elems) = 144 B

typedef __attribute__((ext_vector_type(8))) short bf16x8;
typedef __attribute__((ext_vector_type(4))) float f32x4;
typedef __attribute__((ext_vector_type(4))) float fv4;
typedef __attribute__((ext_vector_type(4))) int iv4;
typedef __attribute__((ext_vector_type(4))) unsigned int u32x4;
typedef __attribute__((ext_vector_type(4))) unsigned short us4;

__device__ __forceinline__ uint32_t pack_bf16(float a, float b) {
  // exact for integer-valued floats |v| <= 255
  return (__float_as_uint(a) >> 16) | (__float_as_uint(b) & 0xFFFF0000u);
}

// Prepass: weight fp32 -> bf16 (65536 elems; stays L2/LLC-resident, 128 KB)
__global__ void wconv(const float* __restrict__ w, unsigned short* __restrict__ wb) {
  const int i = blockIdx.x * 256 + threadIdx.x;
  const fv4 f = ((const fv4*)w)[i];
  us4 o;
  o.x = (unsigned short)(__float_as_uint(f.x) >> 16);
  o.y = (unsigned short)(__float_as_uint(f.y) >> 16);
  o.z = (unsigned short)(__float_as_uint(f.z) >> 16);
  o.w = (unsigned short)(__float_as_uint(f.w) >> 16);
  ((us4*)wb)[i] = o;
}

// Shared GEMM body: computes acc[4][4] (f32x4) for this block/wave.
// 256 threads (4 waves); block tile 64 x 256 (full N); wave w: cols w*64..+63.
// Regular (cached) act loads -- we WANT act resident in LLC for the recompute.
__device__ __forceinline__ void gemm_tile(
    const float* __restrict__ act, const unsigned short* __restrict__ wgtb,
    short* As, short* Bs, f32x4 acc[4][4])
{
  const int tid  = threadIdx.x;
  const int bm   = blockIdx.x * BM;
  const int lane = tid & 63;
  const int wave = tid >> 6;
  const int lm   = lane & 15;
  const int lk   = lane >> 4;
  const int wn   = wave * 64;

  const int arow = tid >> 3, aks = (tid & 7) * 8;   // A: 2 chunks (8 fp32->bf16)
  const int brow = tid >> 3, bks = (tid & 7) * 8;   // B: 8 chunks (8 bf16)

  uint32_t apk[2][4];
  u32x4 breg[8];

#pragma unroll
  for (int j = 0; j < 2; ++j) {
    const float* p = act + (size_t)(bm + arow + j * 32) * NK + aks;
    const fv4 f0 = *(const fv4*)p;
    const fv4 f1 = *((const fv4*)p + 1);
    apk[j][0] = pack_bf16(f0.x, f0.y); apk[j][1] = pack_bf16(f0.z, f0.w);
    apk[j][2] = pack_bf16(f1.x, f1.y); apk[j][3] = pack_bf16(f1.z, f1.w);
  }
#pragma unroll
  for (int j = 0; j < 8; ++j)
    breg[j] = *(const u32x4*)(wgtb + (size_t)(brow + j * 32) * NK + bks);

  for (int kt = 0; kt < NK; kt += BK) {
    __syncthreads();
#pragma unroll
    for (int j = 0; j < 2; ++j)
      *(u32x4*)&As[(arow + j * 32) * BKP + aks] = *(const u32x4*)apk[j];
#pragma unroll
    for (int j = 0; j < 8; ++j)
      *(u32x4*)&Bs[(brow + j * 32) * BKP + bks] = breg[j];
    __syncthreads();

    if (kt + BK < NK) {
      const int ktn = kt + BK;
#pragma unroll
      for (int j = 0; j < 2; ++j) {
        const float* p = act + (size_t)(bm + arow + j * 32) * NK + ktn + aks;
        const fv4 f0 = *(const fv4*)p;
        const fv4 f1 = *((const fv4*)p + 1);
        apk[j][0] = pack_bf16(f0.x, f0.y); apk[j][1] = pack_bf16(f0.z, f0.w);
        apk[j][2] = pack_bf16(f1.x, f1.y); apk[j][3] = pack_bf16(f1.z, f1.w);
      }
#pragma unroll
      for (int j = 0; j < 8; ++j)
        breg[j] = *(const u32x4*)(wgtb + (size_t)(brow + j * 32) * NK + ktn + bks);
    }

#pragma unroll
    for (int kk = 0; kk < BK; kk += 32) {
      bf16x8 af[4], bfr[4];
#pragma unroll
      for (int mi = 0; mi < 4; ++mi)
        af[mi] = *(const bf16x8*)&As[(mi * 16 + lm) * BKP + kk + lk * 8];
#pragma unroll
      for (int ni = 0; ni < 4; ++ni)
        bfr[ni] = *(const bf16x8*)&Bs[(wn + ni * 16 + lm) * BKP + kk + lk * 8];
#pragma unroll
      for (int mi = 0; mi < 4; ++mi)
#pragma unroll
        for (int ni = 0; ni < 4; ++ni)
          acc[mi][ni] = __builtin_amdgcn_mfma_f32_16x16x32_bf16(
              af[mi], bfr[ni], acc[mi][ni], 0, 0, 0);
    }
  }
}

// k1: GEMM -> global abs-max only. No output stores.
__global__ __launch_bounds__(256, 3) void gemm_max(
    const float* __restrict__ act, const unsigned short* __restrict__ wgtb,
    int* __restrict__ gmax)
{
  __shared__ __align__(16) short As[BM * BKP];
  __shared__ __align__(16) short Bs[NK * BKP];
  __shared__ int smax;
  const int tid = threadIdx.x;
  if (tid == 0) smax = 0;

  f32x4 acc[4][4] = {};
  gemm_tile(act, wgtb, As, Bs, acc);

  int imax = 0;
#pragma unroll
  for (int mi = 0; mi < 4; ++mi)
#pragma unroll
    for (int ni = 0; ni < 4; ++ni)
#pragma unroll
      for (int r = 0; r < 4; ++r) {
        const int iv = (int)acc[mi][ni][r];
        const int a = iv < 0 ? -iv : iv;
        imax = a > imax ? a : imax;
      }
#pragma unroll
  for (int off = 32; off; off >>= 1) {
    const int o = __shfl_xor(imax, off, 64);
    imax = o > imax ? o : imax;
  }
  if ((tid & 63) == 0) atomicMax(&smax, imax);
  __syncthreads();
  if (tid == 0) atomicMax(gmax, smax);
}

// k2: recompute GEMM, quantize in registers, nt-store final int32 output.
__global__ __launch_bounds__(256, 3) void gemm_quant(
    const float* __restrict__ act, const unsigned short* __restrict__ wgtb,
    int* __restrict__ out, const int* __restrict__ gmax,
    const int* __restrict__ exp_in, const int* __restrict__ wexp)
{
  __shared__ __align__(16) short As[BM * BKP];
  __shared__ __align__(16) short Bs[NK * BKP];

  const int rmax = *gmax;
  const int bw = (rmax <= 1) ? 0 : (32 - __clz(rmax - 1));   // ceil(log2(r))
  const int shift = bw - 7;
  const bool pos = shift > 0;
  const int s = shift < 1 ? 1 : shift;

  f32x4 acc[4][4] = {};
  gemm_tile(act, wgtb, As, Bs, acc);

  const int tid  = threadIdx.x;
  const int bm   = blockIdx.x * BM;
  const int lane = tid & 63;
  const int lm   = lane & 15;
  const int lk   = lane >> 4;
  const int wn   = (tid >> 6) * 64;

#pragma unroll
  for (int mi = 0; mi < 4; ++mi)
#pragma unroll
    for (int ni = 0; ni < 4; ++ni)
#pragma unroll
      for (int r = 0; r < 4; ++r) {
        const int ti = (int)acc[mi][ni][r];
        int q;
        if (pos) {
          const int rt = ti >> s;                       // floor(t / 2^s)
          const int dec = (ti - (rt << s)) >> (s - 1);  // {0,1}
          q = rt + dec;
          q = q > 127 ? 127 : (q < -127 ? -127 : q);
        } else {
          q = (int)(signed char)(ti & 0xFF);            // int8 wrap
        }
        const int m = bm + mi * 16 + lk * 4 + r;
        const int n = wn + ni * 16 + lm;
        __builtin_nontemporal_store(q, &out[(size_t)m * NK + n]);
      }

  if (blockIdx.x == 0 && tid == 0) {
    const int e = exp_in[0] + wexp[0] + (pos ? shift : 0);
    out[(size_t)M_ROWS * NK] = (int)(short)e;
  }
}

extern "C" void kernel_launch(void* const* d_in, const int* in_sizes, int n_in,
                              void* d_out, int out_size, void* d_ws, size_t ws_size,
                              hipStream_t stream) {
  const float* act   = (const float*)d_in[0];
  const int* exp_in  = (const int*)d_in[1];
  const float* wgt   = (const float*)d_in[2];
  const int* wexp    = (const int*)d_in[3];
  int* gmax          = (int*)d_ws;
  unsigned short* wb = (unsigned short*)((char*)d_ws + 128);  // 128 KB bf16 weight

  (void)hipMemsetAsync(d_ws, 0, sizeof(int), stream);
  wconv<<<dim3(64), dim3(256), 0, stream>>>(wgt, wb);
  gemm_max<<<dim3(M_ROWS / BM), dim3(256), 0, stream>>>(act, wb, gmax);
  gemm_quant<<<dim3(M_ROWS / BM), dim3(256), 0, stream>>>(act, wb, (int*)d_out,
                                                          gmax, exp_in, wexp);
}